// Round 12
// baseline (16790.468 us; speedup 1.0000x reference)
//
#include <hip/hip_runtime.h>

#define HH 512
#define OO 256
#define BB 64
#define SS 1024
#define TT 256
#define KK 1280   // H(ctx) + O(target) + H(h)

typedef __attribute__((ext_vector_type(8))) short bh8;
typedef __attribute__((ext_vector_type(8))) _Float16 hf8;
typedef __attribute__((ext_vector_type(4))) float fx4;
typedef unsigned short ushort_t;

__device__ __forceinline__ ushort_t f2bf(float x) {
    union { float f; unsigned int u; } v; v.f = x;
    unsigned int r = v.u + 0x7fffu + ((v.u >> 16) & 1u);
    return (ushort_t)(r >> 16);
}
__device__ __forceinline__ float bf2f(ushort_t s) {
    union { unsigned int u; float f; } z; z.u = ((unsigned int)s) << 16; return z.f;
}

// Pack W_cat = [W_ih | W_hh] (j-permuted; see round-0 comment) into MFMA
// B-fragment-major bf16 hi/lo split: W = hi + lo, lo = bf16(W - f32(hi)).
__global__ void prep_weights(const float* __restrict__ W_ih,
                             const float* __restrict__ W_hh,
                             ushort_t* __restrict__ wfH,
                             ushort_t* __restrict__ wfL) {
    int g = blockIdx.x * 256 + threadIdx.x;     // 64*40*2*64 = 327680 groups
    if (g >= 64 * 40 * 2 * 64) return;
    int lane = g & 63;
    int nt = (g >> 6) & 1;
    int kk = (g >> 7) % 40;
    int ht = (g >> 7) / 40;
    int c = nt * 16 + (lane & 15);
    int gate = c >> 3, rr = c & 7;
    int j = gate * 512 + ht * 8 + rr;
    int kbase = kk * 32 + (lane >> 4) * 8;
    ushort_t* dh = wfH + (size_t)g * 8;
    ushort_t* dl = wfL + (size_t)g * 8;
#pragma unroll
    for (int r = 0; r < 8; ++r) {
        int k = kbase + r;
        float v = (k < 768) ? W_ih[(size_t)j * 768 + k]
                            : W_hh[(size_t)j * 512 + (k - 768)];
        ushort_t hi = f2bf(v);
        dh[r] = hi;
        dl[r] = f2bf(v - bf2f(hi));
    }
}

__global__ void prep_misc(const float* __restrict__ hidden,
                          const float* __restrict__ cell,
                          float* __restrict__ h, float* __restrict__ c) {
    const int total = 32768 + 32768;
    for (int i = blockIdx.x * 256 + threadIdx.x; i < total; i += gridDim.x * 256) {
        if (i < 32768) h[i] = hidden[i];
        else           c[i - 32768] = cell[i - 32768];
    }
}

// Tiled transpose: encT[b][k][s] = (fp16) enc[b][s][k]. 64x64 tiles via LDS.
__global__ void prep_encT(const float* __restrict__ enc,
                          _Float16* __restrict__ encT) {
    __shared__ _Float16 tile[64][65];
    const int tid = threadIdx.x;
    const int lane = tid & 63, quad = tid >> 6;
    const int bid = blockIdx.x;            // 64 b x 16 st x 8 kt = 8192
    const int b = bid >> 7;
    const int st = (bid >> 3) & 15;
    const int kt = bid & 7;
#pragma unroll
    for (int i = 0; i < 16; ++i) {
        const int r = quad * 16 + i;       // s within tile
        tile[r][lane] = (_Float16)enc[((size_t)(b * SS + st * 64 + r)) * HH
                                      + kt * 64 + lane];
    }
    __syncthreads();
#pragma unroll
    for (int i = 0; i < 16; ++i) {
        const int kr = quad * 16 + i;      // k within tile
        encT[((size_t)(b * HH + kt * 64 + kr)) * SS + st * 64 + lane] =
            tile[lane][kr];
    }
}

// Straight fp32 -> fp16 copy of enc (same [b][s][k] layout), 8 elems/thread.
__global__ void prep_ench(const float* __restrict__ enc,
                          _Float16* __restrict__ ench) {
    const size_t i = ((size_t)blockIdx.x * 256 + threadIdx.x) * 8;
    const float4 a = *(const float4*)(enc + i);
    const float4 b = *(const float4*)(enc + i + 4);
    hf8 o;
    o[0] = (_Float16)a.x; o[1] = (_Float16)a.y;
    o[2] = (_Float16)a.z; o[3] = (_Float16)a.w;
    o[4] = (_Float16)b.x; o[5] = (_Float16)b.y;
    o[6] = (_Float16)b.z; o[7] = (_Float16)b.w;
    *(hf8*)(ench + i) = o;
}

// FC for one (b, oq) unit; fp32 W_fc rows (summation order as R4-R9).
__device__ __forceinline__ void fc_unit(int v, int tprev,
                                        const float* __restrict__ h,
                                        const float* __restrict__ W_fc,
                                        const float* __restrict__ b_fc,
                                        float* __restrict__ out,
                                        float (*shacc)[64]) {
    const int tid = threadIdx.x;
    const int b = v >> 2, oq = v & 3;
    const int ol = tid & 63, kq = tid >> 6;
    const int o = oq * 64 + ol;
    float acc = 0.f;
    const float* hp = h + b * HH + kq * 128;
    const float* wp = W_fc + (size_t)o * HH + kq * 128;
#pragma unroll 8
    for (int k2 = 0; k2 < 128; ++k2) acc += hp[k2] * wp[k2];
    shacc[kq][ol] = acc;
    __syncthreads();
    if (tid < 64) {
        float vv = shacc[0][tid] + shacc[1][tid]
                 + shacc[2][tid] + shacc[3][tid] + b_fc[oq * 64 + tid];
        out[((size_t)b * TT + tprev) * OO + oq * 64 + tid] = vv;
    }
}

// K1: blocks 0..255 = attention partial for (b, S-quarter qs) with NO per-row
// cross-lane reduce: phase1 thread-owns-one-s streaming dot (encT, h bcast),
// one block softmax, phase2 thread-owns-two-k streaming weighted sum.
// Blocks 256..511 = FC producing out[t-1]. Fence-free.
template <int PH2F16>
__global__ void __launch_bounds__(256)
step_attn5(int t, const _Float16* __restrict__ encT,
           const _Float16* __restrict__ ench, const float* __restrict__ enc32,
           const float* __restrict__ h,
           float* __restrict__ pm4, float* __restrict__ pl4,
           float* __restrict__ pctx4,
           const float* __restrict__ W_fc, const float* __restrict__ b_fc,
           float* __restrict__ out) {
    const int tid = threadIdx.x;
    const int lane = tid & 63;
    const int w = tid >> 6;

    __shared__ union {
        struct { float h[512]; float p[256]; float wm[4]; float wl[4]; } a;
        struct { float acc[4][64]; } o;
    } sh;

    const int u = blockIdx.x;
    if (u < 256) {
        const int b = u >> 2, qs = u & 3;
        {   // stage h[b] into LDS
            const float2 hv = *(const float2*)(h + b * HH + tid * 2);
            sh.a.h[tid * 2]     = hv.x;
            sh.a.h[tid * 2 + 1] = hv.y;
        }
        __syncthreads();
        // ---- phase 1: score for s = qs*256 + tid (4 indep accumulators) ----
        const _Float16* ep = encT + ((size_t)b * HH) * SS + qs * 256 + tid;
        float a0 = 0.f, a1 = 0.f, a2 = 0.f, a3 = 0.f;
        for (int k = 0; k < 512; k += 4) {
            const float4 hv = *(const float4*)&sh.a.h[k];
            a0 += hv.x * (float)ep[(size_t)(k + 0) * SS];
            a1 += hv.y * (float)ep[(size_t)(k + 1) * SS];
            a2 += hv.z * (float)ep[(size_t)(k + 2) * SS];
            a3 += hv.w * (float)ep[(size_t)(k + 3) * SS];
        }
        const float sc = (a0 + a1) + (a2 + a3);
        // ---- block softmax (shuffles once per step, not per row) ----
        float m = sc;
#pragma unroll
        for (int off = 32; off; off >>= 1) m = fmaxf(m, __shfl_xor(m, off));
        if (lane == 0) sh.a.wm[w] = m;
        __syncthreads();
        const float M = fmaxf(fmaxf(sh.a.wm[0], sh.a.wm[1]),
                              fmaxf(sh.a.wm[2], sh.a.wm[3]));
        const float p = __expf(sc - M);
        sh.a.p[tid] = p;
        float l = p;
#pragma unroll
        for (int off = 32; off; off >>= 1) l += __shfl_xor(l, off);
        if (lane == 0) sh.a.wl[w] = l;
        __syncthreads();
        if (tid == 0) {
            pm4[b * 4 + qs] = M;
            pl4[b * 4 + qs] = sh.a.wl[0] + sh.a.wl[1] + sh.a.wl[2] + sh.a.wl[3];
        }
        // ---- phase 2: unnormalized ctx partial; thread owns k0=2*tid ----
        float c0 = 0.f, c1 = 0.f;
        if (PH2F16) {
            const _Float16* e2 =
                ench + ((size_t)(b * SS + qs * 256)) * HH + tid * 2;
            for (int s = 0; s < 256; ++s) {
                const float ps = sh.a.p[s];
                c0 += ps * (float)e2[0];
                c1 += ps * (float)e2[1];
                e2 += HH;
            }
        } else {
            const float* e2 = enc32 + ((size_t)(b * SS + qs * 256)) * HH + tid * 2;
            for (int s = 0; s < 256; ++s) {
                const float ps = sh.a.p[s];
                const float2 ev = *(const float2*)e2;
                c0 += ps * ev.x;
                c1 += ps * ev.y;
                e2 += HH;
            }
        }
        float* pc = pctx4 + ((size_t)(b * 4 + qs)) * 512 + tid * 2;
        pc[0] = c0;
        pc[1] = c1;
    } else if (t > 0) {
        fc_unit(u - 256, t - 1, h, W_fc, b_fc, out, sh.o.acc);
    }
}

// K2: gates MFMA with inline 4-partial softmax-combine A-construction (fp32
// partials) + cell update. Reads hin, writes hout (double buffer).
__global__ void __launch_bounds__(256)
step_gates5(int t, const float* __restrict__ pm4, const float* __restrict__ pl4,
            const float* __restrict__ pctx4,
            const float* __restrict__ target, const float* __restrict__ hin,
            const ushort_t* __restrict__ wfH, const ushort_t* __restrict__ wfL,
            const float* __restrict__ b_ih, const float* __restrict__ b_hh,
            float* __restrict__ hout, float* __restrict__ c) {
    const int tid = threadIdx.x;
    const int lane = tid & 63;
    const int w = tid >> 6;
    __shared__ float g[64][32];
    __shared__ float cw[64][4];

    if (tid < 64) {
        const int b = tid;
        const float p0 = pm4[b*4+0], p1 = pm4[b*4+1];
        const float p2 = pm4[b*4+2], p3 = pm4[b*4+3];
        const float M = fmaxf(fmaxf(p0, p1), fmaxf(p2, p3));
        const float w0 = __expf(p0 - M), w1 = __expf(p1 - M);
        const float w2 = __expf(p2 - M), w3 = __expf(p3 - M);
        const float inv = 1.0f / (w0 * pl4[b*4+0] + w1 * pl4[b*4+1]
                                + w2 * pl4[b*4+2] + w3 * pl4[b*4+3]);
        cw[b][0] = w0 * inv; cw[b][1] = w1 * inv;
        cw[b][2] = w2 * inv; cw[b][3] = w3 * inv;
    }
    __syncthreads();

    const int ht = blockIdx.x;
    fx4 a0 = {0, 0, 0, 0}, a1 = {0, 0, 0, 0};
    const int bro = 16 * w + (lane & 15);
    const int kg = lane >> 4;
    const size_t wbase = (size_t)ht * 40 * 2 * 512;
    const float cw0 = cw[bro][0], cw1 = cw[bro][1];
    const float cw2 = cw[bro][2], cw3 = cw[bro][3];
    const float* pc0 = pctx4 + ((size_t)(bro * 4 + 0)) * 512;
    const float* pc1 = pctx4 + ((size_t)(bro * 4 + 1)) * 512;
    const float* pc2 = pctx4 + ((size_t)(bro * 4 + 2)) * 512;
    const float* pc3 = pctx4 + ((size_t)(bro * 4 + 3)) * 512;

#define GATES_MFMA_STEP(kkv)                                                   \
    {                                                                          \
        bh8 b0h = *(const bh8*)(wfH + wbase + ((kkv) * 2 + 0) * 512 + lane*8); \
        bh8 b1h = *(const bh8*)(wfH + wbase + ((kkv) * 2 + 1) * 512 + lane*8); \
        bh8 b0l = *(const bh8*)(wfL + wbase + ((kkv) * 2 + 0) * 512 + lane*8); \
        bh8 b1l = *(const bh8*)(wfL + wbase + ((kkv) * 2 + 1) * 512 + lane*8); \
        a0 = __builtin_amdgcn_mfma_f32_16x16x32_bf16(avh, b0h, a0, 0, 0, 0);   \
        a0 = __builtin_amdgcn_mfma_f32_16x16x32_bf16(avl, b0h, a0, 0, 0, 0);   \
        a0 = __builtin_amdgcn_mfma_f32_16x16x32_bf16(avh, b0l, a0, 0, 0, 0);   \
        a1 = __builtin_amdgcn_mfma_f32_16x16x32_bf16(avh, b1h, a1, 0, 0, 0);   \
        a1 = __builtin_amdgcn_mfma_f32_16x16x32_bf16(avl, b1h, a1, 0, 0, 0);   \
        a1 = __builtin_amdgcn_mfma_f32_16x16x32_bf16(avh, b1l, a1, 0, 0, 0);   \
    }

    // ctx region: kk 0..15
    for (int kk = 0; kk < 16; ++kk) {
        const int k0 = kk * 32 + kg * 8;
        bh8 avh, avl;
#pragma unroll
        for (int j = 0; j < 8; ++j) {
            const float s = cw0 * pc0[k0 + j] + cw1 * pc1[k0 + j]
                          + cw2 * pc2[k0 + j] + cw3 * pc3[k0 + j];
            const ushort_t hi = f2bf(s);
            avh[j] = (short)hi;
            avl[j] = (short)f2bf(s - bf2f(hi));
        }
        GATES_MFMA_STEP(kk)
    }
    // target region: kk 16..23
    {
        const float* tb = target + ((size_t)bro * TT + t) * OO + kg * 8 - 512;
        for (int kk = 16; kk < 24; ++kk) {
            const float* tp = tb + kk * 32;
            bh8 avh, avl;
#pragma unroll
            for (int j = 0; j < 8; ++j) {
                const float s = tp[j];
                const ushort_t hi = f2bf(s);
                avh[j] = (short)hi;
                avl[j] = (short)f2bf(s - bf2f(hi));
            }
            GATES_MFMA_STEP(kk)
        }
    }
    // h region: kk 24..39
    {
        const float* hb = hin + bro * HH + kg * 8 - 768;
        for (int kk = 24; kk < 40; ++kk) {
            const float* hp = hb + kk * 32;
            bh8 avh, avl;
#pragma unroll
            for (int j = 0; j < 8; ++j) {
                const float s = hp[j];
                const ushort_t hi = f2bf(s);
                avh[j] = (short)hi;
                avl[j] = (short)f2bf(s - bf2f(hi));
            }
            GATES_MFMA_STEP(kk)
        }
    }
#undef GATES_MFMA_STEP

    const int crow = (lane >> 4) * 4;
#pragma unroll
    for (int r = 0; r < 4; ++r) {
        g[16 * w + crow + r][lane & 15]        = a0[r];
        g[16 * w + crow + r][16 + (lane & 15)] = a1[r];
    }
    __syncthreads();
#pragma unroll
    for (int p = 0; p < 2; ++p) {
        const int idx = tid * 2 + p;
        const int b = idx >> 3, r = idx & 7;
        const int hidx = ht * 8 + r;
        float gi = g[b][r]      + b_ih[hidx]        + b_hh[hidx];
        float gf = g[b][8 + r]  + b_ih[512 + hidx]  + b_hh[512 + hidx];
        float gg = g[b][16 + r] + b_ih[1024 + hidx] + b_hh[1024 + hidx];
        float go = g[b][24 + r] + b_ih[1536 + hidx] + b_hh[1536 + hidx];
        float ig = 1.f / (1.f + __expf(-gi));
        float fg = 1.f / (1.f + __expf(-gf));
        float g2 = tanhf(gg);
        float og = 1.f / (1.f + __expf(-go));
        float cn = fg * c[b * HH + hidx] + ig * g2;
        float hn = og * tanhf(cn);
        c[b * HH + hidx] = cn;
        hout[b * HH + hidx] = hn;
    }
}

// Final FC: out[TT-1] from final h (256 blocks x 256 thr, R9 layout).
__global__ void __launch_bounds__(256)
fc_final(const float* __restrict__ h, const float* __restrict__ W_fc,
         const float* __restrict__ b_fc, float* __restrict__ out) {
    __shared__ float acc[4][64];
    fc_unit(blockIdx.x, TT - 1, h, W_fc, b_fc, out, acc);
}

extern "C" void kernel_launch(void* const* d_in, const int* in_sizes, int n_in,
                              void* d_out, int out_size, void* d_ws, size_t ws_size,
                              hipStream_t stream) {
    const float* enc    = (const float*)d_in[0];
    const float* hidden = (const float*)d_in[1];
    const float* cellp  = (const float*)d_in[2];
    const float* target = (const float*)d_in[3];
    const float* W_ih   = (const float*)d_in[4];
    const float* W_hh   = (const float*)d_in[5];
    const float* b_ih   = (const float*)d_in[6];
    const float* b_hh   = (const float*)d_in[7];
    const float* W_fc   = (const float*)d_in[8];
    const float* b_fc   = (const float*)d_in[9];
    float* out = (float*)d_out;

    char* base = (char*)d_ws;
    float* hA          = (float*)(base + 0);                 // 131,072 B
    float* hB          = (float*)(base + 131072);            // 131,072 B
    float* c           = (float*)(base + 262144);            // 131,072 B
    ushort_t* wfH      = (ushort_t*)(base + 393216);         // 5,242,880 B
    ushort_t* wfL      = (ushort_t*)(base + 5636096);        // 5,242,880 B
    float* pm4         = (float*)(base + 10878976);          // 1,024 B
    float* pl4         = (float*)(base + 10880000);          // 1,024 B
    float* pctx4       = (float*)(base + 10881024);          // 524,288 B
    _Float16* encT     = (_Float16*)(base + 11405312);       // 67,108,864 B
    _Float16* ench     = (_Float16*)(base + 78514176);       // 67,108,864 B (optional)
    const size_t NEED_DUAL = 78514176ULL + 67108864ULL;      // 145,623,040 B

    const bool f16p2 = (ws_size >= NEED_DUAL);

    prep_weights<<<dim3(1280), dim3(256), 0, stream>>>(W_ih, W_hh, wfH, wfL);
    prep_misc<<<dim3(256), dim3(256), 0, stream>>>(hidden, cellp, hA, c);
    prep_encT<<<dim3(8192), dim3(256), 0, stream>>>(enc, encT);
    if (f16p2)
        prep_ench<<<dim3(16384), dim3(256), 0, stream>>>(enc, ench);

    for (int t = 0; t < TT; ++t) {
        float* hcur = (t & 1) ? hB : hA;
        float* hnxt = (t & 1) ? hA : hB;
        if (f16p2)
            step_attn5<1><<<dim3(512), dim3(256), 0, stream>>>(
                t, encT, ench, enc, hcur, pm4, pl4, pctx4, W_fc, b_fc, out);
        else
            step_attn5<0><<<dim3(512), dim3(256), 0, stream>>>(
                t, encT, ench, enc, hcur, pm4, pl4, pctx4, W_fc, b_fc, out);
        step_gates5<<<dim3(64), dim3(256), 0, stream>>>(
            t, pm4, pl4, pctx4, target, hcur, wfH, wfL, b_ih, b_hh, hnxt, c);
    }
    // TT even -> final h is hA
    fc_final<<<dim3(256), dim3(256), 0, stream>>>(hA, W_fc, b_fc, out);
}

// Round 13
// 12974.939 us; speedup vs baseline: 1.2941x; 1.2941x over previous
//
#include <hip/hip_runtime.h>

#define HH 512
#define OO 256
#define BB 64
#define SS 1024
#define TT 256
#define KK 1280   // H(ctx) + O(target) + H(h)

typedef __attribute__((ext_vector_type(8))) short bh8;
typedef __attribute__((ext_vector_type(8))) _Float16 hf8;
typedef __attribute__((ext_vector_type(4))) float fx4;
typedef unsigned short ushort_t;

__device__ __forceinline__ ushort_t f2bf(float x) {
    union { float f; unsigned int u; } v; v.f = x;
    unsigned int r = v.u + 0x7fffu + ((v.u >> 16) & 1u);
    return (ushort_t)(r >> 16);
}
__device__ __forceinline__ float bf2f(ushort_t s) {
    union { unsigned int u; float f; } z; z.u = ((unsigned int)s) << 16; return z.f;
}

// Pack W_cat = [W_ih | W_hh] (j-permuted; see round-0 comment) into MFMA
// B-fragment-major bf16 hi/lo split: W = hi + lo, lo = bf16(W - f32(hi)).
__global__ void prep_weights(const float* __restrict__ W_ih,
                             const float* __restrict__ W_hh,
                             ushort_t* __restrict__ wfH,
                             ushort_t* __restrict__ wfL) {
    int g = blockIdx.x * 256 + threadIdx.x;     // 64*40*2*64 = 327680 groups
    if (g >= 64 * 40 * 2 * 64) return;
    int lane = g & 63;
    int nt = (g >> 6) & 1;
    int kk = (g >> 7) % 40;
    int ht = (g >> 7) / 40;
    int c = nt * 16 + (lane & 15);
    int gate = c >> 3, rr = c & 7;
    int j = gate * 512 + ht * 8 + rr;
    int kbase = kk * 32 + (lane >> 4) * 8;
    ushort_t* dh = wfH + (size_t)g * 8;
    ushort_t* dl = wfL + (size_t)g * 8;
#pragma unroll
    for (int r = 0; r < 8; ++r) {
        int k = kbase + r;
        float v = (k < 768) ? W_ih[(size_t)j * 768 + k]
                            : W_hh[(size_t)j * 512 + (k - 768)];
        ushort_t hi = f2bf(v);
        dh[r] = hi;
        dl[r] = f2bf(v - bf2f(hi));
    }
}

__global__ void prep_misc(const float* __restrict__ hidden,
                          const float* __restrict__ cell,
                          float* __restrict__ h, float* __restrict__ c) {
    const int total = 32768 + 32768;
    for (int i = blockIdx.x * 256 + threadIdx.x; i < total; i += gridDim.x * 256) {
        if (i < 32768) h[i] = hidden[i];
        else           c[i - 32768] = cell[i - 32768];
    }
}

// Pack enc into MFMA A-fragment-major fp16 layout (HW-verified mapping:
// A[row][k] with row=lane&15, k=(lane>>4)*8+j — same as the gates kernel).
// Index: ((((b*16+ch)*4+w)*16+kk)*64+lane)*8 + j
//   s = ch*64 + w*16 + (lane&15);  k = kk*32 + (lane>>4)*8 + j
__global__ void prep_encfrag(const float* __restrict__ enc,
                             _Float16* __restrict__ encfrag) {
    const int g = blockIdx.x * 256 + threadIdx.x;   // 2^22 groups
    const int lane = g & 63;
    const int kk = (g >> 6) & 15;
    const int w = (g >> 10) & 3;
    const int ch = (g >> 12) & 15;
    const int b = g >> 16;
    const int s = ch * 64 + w * 16 + (lane & 15);
    const int k0 = kk * 32 + (lane >> 4) * 8;
    const float* src = enc + ((size_t)(b * SS + s)) * HH + k0;
    const float4 a = *(const float4*)src;
    const float4 bb = *(const float4*)(src + 4);
    hf8 o;
    o[0] = (_Float16)a.x;  o[1] = (_Float16)a.y;
    o[2] = (_Float16)a.z;  o[3] = (_Float16)a.w;
    o[4] = (_Float16)bb.x; o[5] = (_Float16)bb.y;
    o[6] = (_Float16)bb.z; o[7] = (_Float16)bb.w;
    *(hf8*)(encfrag + (size_t)g * 8) = o;
}

// Optional: fp32 -> fp16 row-major copy of enc for phase 2 (guarded by ws).
__global__ void prep_ench(const float* __restrict__ enc,
                          _Float16* __restrict__ ench) {
    const size_t i = ((size_t)blockIdx.x * 256 + threadIdx.x) * 8;
    const float4 a = *(const float4*)(enc + i);
    const float4 b = *(const float4*)(enc + i + 4);
    hf8 o;
    o[0] = (_Float16)a.x; o[1] = (_Float16)a.y;
    o[2] = (_Float16)a.z; o[3] = (_Float16)a.w;
    o[4] = (_Float16)b.x; o[5] = (_Float16)b.y;
    o[6] = (_Float16)b.z; o[7] = (_Float16)b.w;
    *(hf8*)(ench + i) = o;
}

// FC for one (b, oq) unit; fp32 W_fc rows (summation order as R4-R9).
__device__ __forceinline__ void fc_unit(int v, int tprev,
                                        const float* __restrict__ h,
                                        const float* __restrict__ W_fc,
                                        const float* __restrict__ b_fc,
                                        float* __restrict__ out,
                                        float (*shacc)[64]) {
    const int tid = threadIdx.x;
    const int b = v >> 2, oq = v & 3;
    const int ol = tid & 63, kq = tid >> 6;
    const int o = oq * 64 + ol;
    float acc = 0.f;
    const float* hp = h + b * HH + kq * 128;
    const float* wp = W_fc + (size_t)o * HH + kq * 128;
#pragma unroll 8
    for (int k2 = 0; k2 < 128; ++k2) acc += hp[k2] * wp[k2];
    shacc[kq][ol] = acc;
    __syncthreads();
    if (tid < 64) {
        float vv = shacc[0][tid] + shacc[1][tid]
                 + shacc[2][tid] + shacc[3][tid] + b_fc[oq * 64 + tid];
        out[((size_t)b * TT + tprev) * OO + oq * 64 + tid] = vv;
    }
}

// K1: blocks 0..1023 = attention partial for (b, 64-row chunk ch):
//   phase 1: scores via MFMA (encfrag x h_fp16), 2 shuffles/wave softmax
//   phase 2: streaming ctx partial (p broadcast from LDS, coalesced rows)
// Blocks 1024..1279: FC producing out[t-1]. Fence-free.
template <int PH2F16>
__global__ void __launch_bounds__(256)
step_attn6(int t, const _Float16* __restrict__ encfrag,
           const _Float16* __restrict__ ench, const float* __restrict__ enc32,
           const float* __restrict__ h,
           float* __restrict__ pm, float* __restrict__ pl,
           float* __restrict__ pctx,
           const float* __restrict__ W_fc, const float* __restrict__ b_fc,
           float* __restrict__ out) {
    const int tid = threadIdx.x;
    const int lane = tid & 63;
    const int w = tid >> 6;

    __shared__ union {
        struct { _Float16 h16[512]; float p[64]; float wm[4]; float wl[4]; } a;
        struct { float acc[4][64]; } o;
    } sh;

    const int u = blockIdx.x;
    if (u < 1024) {
        const int b = u >> 4, ch = u & 15;
        {   // stage h[b] as fp16 into LDS
            const float2 hv = *(const float2*)(h + b * HH + tid * 2);
            sh.a.h16[tid * 2]     = (_Float16)hv.x;
            sh.a.h16[tid * 2 + 1] = (_Float16)hv.y;
        }
        __syncthreads();
        // ---- phase 1: scores for the wave's 16 rows via MFMA ----
        const _Float16* af = encfrag + ((size_t)(u * 4 + w) * 16) * 512;
        fx4 acc = {0.f, 0.f, 0.f, 0.f};
#pragma unroll
        for (int kk = 0; kk < 16; ++kk) {
            const hf8 afr = *(const hf8*)(af + kk * 512 + lane * 8);
            const hf8 bfr = *(const hf8*)&sh.a.h16[kk * 32 + (lane >> 4) * 8];
            acc = __builtin_amdgcn_mfma_f32_16x16x32_f16(afr, bfr, acc, 0, 0, 0);
        }
        // lane holds rows (lane>>4)*4 + r (cols replicated). Wave softmax:
        float m4 = fmaxf(fmaxf(acc[0], acc[1]), fmaxf(acc[2], acc[3]));
        float m16 = fmaxf(m4, __shfl_xor(m4, 16));
        m16 = fmaxf(m16, __shfl_xor(m16, 32));
        float e0 = __expf(acc[0] - m16), e1 = __expf(acc[1] - m16);
        float e2 = __expf(acc[2] - m16), e3 = __expf(acc[3] - m16);
        float l4 = (e0 + e1) + (e2 + e3);
        float l16 = l4 + __shfl_xor(l4, 16);
        l16 += __shfl_xor(l16, 32);
        if (lane == 0) { sh.a.wm[w] = m16; sh.a.wl[w] = l16; }
        __syncthreads();
        const float M = fmaxf(fmaxf(sh.a.wm[0], sh.a.wm[1]),
                              fmaxf(sh.a.wm[2], sh.a.wm[3]));
        if ((lane & 15) == 0) {
            const int rbase = w * 16 + (lane >> 4) * 4;
            sh.a.p[rbase + 0] = __expf(acc[0] - M);
            sh.a.p[rbase + 1] = __expf(acc[1] - M);
            sh.a.p[rbase + 2] = __expf(acc[2] - M);
            sh.a.p[rbase + 3] = __expf(acc[3] - M);
        }
        if (tid == 0) {
            const float pls = sh.a.wl[0] * __expf(sh.a.wm[0] - M)
                            + sh.a.wl[1] * __expf(sh.a.wm[1] - M)
                            + sh.a.wl[2] * __expf(sh.a.wm[2] - M)
                            + sh.a.wl[3] * __expf(sh.a.wm[3] - M);
            pm[u] = M;
            pl[u] = pls;
        }
        __syncthreads();
        // ---- phase 2: unnormalized ctx partial; thread owns k0 = 2*tid ----
        const int k0 = tid * 2;
        float c0 = 0.f, c1 = 0.f;
        if (PH2F16) {
            const _Float16* e2p = ench + ((size_t)(b * SS + ch * 64)) * HH + k0;
            for (int s = 0; s < 64; ++s) {
                const float ps = sh.a.p[s];
                c0 += ps * (float)e2p[0];
                c1 += ps * (float)e2p[1];
                e2p += HH;
            }
        } else {
            const float* e2p = enc32 + ((size_t)(b * SS + ch * 64)) * HH + k0;
            for (int s = 0; s < 64; ++s) {
                const float ps = sh.a.p[s];
                const float2 ev = *(const float2*)e2p;
                c0 += ps * ev.x;
                c1 += ps * ev.y;
                e2p += HH;
            }
        }
        float* pc = pctx + (size_t)u * 512 + k0;
        pc[0] = c0;
        pc[1] = c1;
    } else if (t > 0) {
        fc_unit(u - 1024, t - 1, h, W_fc, b_fc, out, sh.o.acc);
    }
}

// Fence-free combine: block b merges 16 chunk partials -> xb hi/lo (bf16
// split), packs target(t) and h. (R9 verbatim.)
__global__ void __launch_bounds__(256)
step_combine(int t, const float* __restrict__ target, const float* __restrict__ h,
             const float* __restrict__ pm, const float* __restrict__ pl,
             const float* __restrict__ pctx,
             ushort_t* __restrict__ xbh, ushort_t* __restrict__ xbl) {
    const int tid = threadIdx.x;
    const int b = blockIdx.x;
    float Mb = -3.0e38f;
#pragma unroll
    for (int q2 = 0; q2 < 16; ++q2) Mb = fmaxf(Mb, pm[b * 16 + q2]);
    float wq[16]; float lsb = 0.f;
#pragma unroll
    for (int q2 = 0; q2 < 16; ++q2) {
        wq[q2] = __expf(pm[b * 16 + q2] - Mb);
        lsb += wq[q2] * pl[b * 16 + q2];
    }
    const float inv = 1.0f / lsb;
    const int h2 = tid * 2;
    float s0 = 0.f, s1 = 0.f;
#pragma unroll
    for (int q2 = 0; q2 < 16; ++q2) {
        const float* pc2 = pctx + ((size_t)(b * 16 + q2)) * HH + h2;
        s0 += wq[q2] * pc2[0];
        s1 += wq[q2] * pc2[1];
    }
    s0 *= inv; s1 *= inv;
    ushort_t a0 = f2bf(s0), a1 = f2bf(s1);
    xbh[b * KK + h2]     = a0;  xbl[b * KK + h2]     = f2bf(s0 - bf2f(a0));
    xbh[b * KK + h2 + 1] = a1;  xbl[b * KK + h2 + 1] = f2bf(s1 - bf2f(a1));
    if (tid < 128) {
        const float* tg = target + ((size_t)b * TT + t) * OO + tid * 2;
        ushort_t t0 = f2bf(tg[0]), t1 = f2bf(tg[1]);
        xbh[b * KK + 512 + tid * 2]     = t0;
        xbh[b * KK + 512 + tid * 2 + 1] = t1;
        xbl[b * KK + 512 + tid * 2]     = f2bf(tg[0] - bf2f(t0));
        xbl[b * KK + 512 + tid * 2 + 1] = f2bf(tg[1] - bf2f(t1));
    }
    const float hv0 = h[b * HH + h2], hv1 = h[b * HH + h2 + 1];
    ushort_t g0 = f2bf(hv0), g1 = f2bf(hv1);
    xbh[b * KK + 768 + h2]     = g0;  xbl[b * KK + 768 + h2]     = f2bf(hv0 - bf2f(g0));
    xbh[b * KK + 768 + h2 + 1] = g1;  xbl[b * KK + 768 + h2 + 1] = f2bf(hv1 - bf2f(g1));
}

// One block per h-tile: split-bf16 gates GEMM (xh*Wh + xl*Wh + xh*Wl) + cell.
// (R9 verbatim.)
__global__ void __launch_bounds__(256)
step_gates(const ushort_t* __restrict__ xbh,
           const ushort_t* __restrict__ xbl,
           const ushort_t* __restrict__ wfH,
           const ushort_t* __restrict__ wfL,
           const float* __restrict__ b_ih, const float* __restrict__ b_hh,
           float* __restrict__ h, float* __restrict__ c) {
    const int tid = threadIdx.x;
    const int lane = tid & 63;
    const int w = tid >> 6;
    __shared__ float g[64][32];

    const int ht = blockIdx.x;
    fx4 a0 = {0, 0, 0, 0}, a1 = {0, 0, 0, 0};
    const int bro = 16 * w + (lane & 15);
    const int kg = lane >> 4;
    const size_t wbase = (size_t)ht * 40 * 2 * 512;
    for (int kk = 0; kk < 40; ++kk) {
        const size_t aoff = (size_t)bro * KK + kk * 32 + kg * 8;
        bh8 avh = *(const bh8*)(xbh + aoff);
        bh8 avl = *(const bh8*)(xbl + aoff);
        bh8 b0h = *(const bh8*)(wfH + wbase + (kk * 2 + 0) * 512 + lane * 8);
        bh8 b1h = *(const bh8*)(wfH + wbase + (kk * 2 + 1) * 512 + lane * 8);
        bh8 b0l = *(const bh8*)(wfL + wbase + (kk * 2 + 0) * 512 + lane * 8);
        bh8 b1l = *(const bh8*)(wfL + wbase + (kk * 2 + 1) * 512 + lane * 8);
        a0 = __builtin_amdgcn_mfma_f32_16x16x32_bf16(avh, b0h, a0, 0, 0, 0);
        a0 = __builtin_amdgcn_mfma_f32_16x16x32_bf16(avl, b0h, a0, 0, 0, 0);
        a0 = __builtin_amdgcn_mfma_f32_16x16x32_bf16(avh, b0l, a0, 0, 0, 0);
        a1 = __builtin_amdgcn_mfma_f32_16x16x32_bf16(avh, b1h, a1, 0, 0, 0);
        a1 = __builtin_amdgcn_mfma_f32_16x16x32_bf16(avl, b1h, a1, 0, 0, 0);
        a1 = __builtin_amdgcn_mfma_f32_16x16x32_bf16(avh, b1l, a1, 0, 0, 0);
    }
    const int crow = (lane >> 4) * 4;
#pragma unroll
    for (int r = 0; r < 4; ++r) {
        g[16 * w + crow + r][lane & 15]        = a0[r];
        g[16 * w + crow + r][16 + (lane & 15)] = a1[r];
    }
    __syncthreads();
#pragma unroll
    for (int p = 0; p < 2; ++p) {
        const int idx = tid * 2 + p;
        const int b = idx >> 3, r = idx & 7;
        const int hidx = ht * 8 + r;
        float gi = g[b][r]      + b_ih[hidx]        + b_hh[hidx];
        float gf = g[b][8 + r]  + b_ih[512 + hidx]  + b_hh[512 + hidx];
        float gg = g[b][16 + r] + b_ih[1024 + hidx] + b_hh[1024 + hidx];
        float go = g[b][24 + r] + b_ih[1536 + hidx] + b_hh[1536 + hidx];
        float ig = 1.f / (1.f + __expf(-gi));
        float fg = 1.f / (1.f + __expf(-gf));
        float g2 = tanhf(gg);
        float og = 1.f / (1.f + __expf(-go));
        float cn = fg * c[b * HH + hidx] + ig * g2;
        float hn = og * tanhf(cn);
        c[b * HH + hidx] = cn;
        h[b * HH + hidx] = hn;
    }
}

__global__ void __launch_bounds__(256)
fc_final(const float* __restrict__ h, const float* __restrict__ W_fc,
         const float* __restrict__ b_fc, float* __restrict__ out) {
    __shared__ float acc[4][64];
    fc_unit(blockIdx.x, TT - 1, h, W_fc, b_fc, out, acc);
}

extern "C" void kernel_launch(void* const* d_in, const int* in_sizes, int n_in,
                              void* d_out, int out_size, void* d_ws, size_t ws_size,
                              hipStream_t stream) {
    const float* enc    = (const float*)d_in[0];
    const float* hidden = (const float*)d_in[1];
    const float* cellp  = (const float*)d_in[2];
    const float* target = (const float*)d_in[3];
    const float* W_ih   = (const float*)d_in[4];
    const float* W_hh   = (const float*)d_in[5];
    const float* b_ih   = (const float*)d_in[6];
    const float* b_hh   = (const float*)d_in[7];
    const float* W_fc   = (const float*)d_in[8];
    const float* b_fc   = (const float*)d_in[9];
    float* out = (float*)d_out;

    char* base = (char*)d_ws;
    float* h            = (float*)(base + 0);                  // 131,072 B
    float* c            = (float*)(base + 131072);             // 131,072 B
    ushort_t* wfH       = (ushort_t*)(base + 262144);          // 5,242,880 B
    ushort_t* wfL       = (ushort_t*)(base + 5505024);         // 5,242,880 B
    ushort_t* xbh       = (ushort_t*)(base + 10747904);        // 163,840 B
    ushort_t* xbl       = (ushort_t*)(base + 10911744);        // 163,840 B
    float* pm           = (float*)(base + 11075584);           // 4,096 B
    float* pl           = (float*)(base + 11079680);           // 4,096 B
    float* pctx         = (float*)(base + 11083776);           // 2,097,152 B
    _Float16* encfrag   = (_Float16*)(base + 13180928);        // 67,108,864 B
    // end of mandatory region: 80,289,792 B (== R9's proven-available bound)
    _Float16* ench      = (_Float16*)(base + 80289792);        // optional 67,108,864 B
    const size_t NEED_PH2 = 80289792ULL + 67108864ULL;         // 147,398,656 B

    const bool f16p2 = (ws_size >= NEED_PH2);

    prep_weights<<<dim3(1280), dim3(256), 0, stream>>>(W_ih, W_hh, wfH, wfL);
    prep_misc<<<dim3(256), dim3(256), 0, stream>>>(hidden, cellp, h, c);
    prep_encfrag<<<dim3(16384), dim3(256), 0, stream>>>(enc, encfrag);
    if (f16p2)
        prep_ench<<<dim3(16384), dim3(256), 0, stream>>>(enc, ench);

    for (int t = 0; t < TT; ++t) {
        if (f16p2)
            step_attn6<1><<<dim3(1280), dim3(256), 0, stream>>>(
                t, encfrag, ench, enc, h, pm, pl, pctx, W_fc, b_fc, out);
        else
            step_attn6<0><<<dim3(1280), dim3(256), 0, stream>>>(
                t, encfrag, ench, enc, h, pm, pl, pctx, W_fc, b_fc, out);
        step_combine<<<dim3(64), dim3(256), 0, stream>>>(
            t, target, h, pm, pl, pctx, xbh, xbl);
        step_gates<<<dim3(64), dim3(256), 0, stream>>>(
            xbh, xbl, wfH, wfL, b_ih, b_hh, h, c);
    }
    fc_final<<<dim3(256), dim3(256), 0, stream>>>(h, W_fc, b_fc, out);
}